// Round 9
// baseline (3830.372 us; speedup 1.0000x reference)
//
#include <hip/hip_runtime.h>
#include <cstdint>
#include <cstddef>

typedef float f4v __attribute__((ext_vector_type(4)));
typedef __bf16 bf8 __attribute__((ext_vector_type(8)));
typedef uint32_t u4v __attribute__((ext_vector_type(4)));

// ---------------- problem constants ----------------
constexpr int cN0 = 100000, cN1 = 200000, cN2 = 100000;
constexpr int cNHE = 20000, cHE = 200000;
constexpr int N0p = 100096, N1p = 200064, N2p = 100096;   // padded to 64-row multiples
constexpr int NTP = N0p + N1p + N2p;
constexpr int CNT_TOT = 1800000;     // sum of row counts over 13 matrices
constexpr int ELLW = 24;             // slots per bucket; bucket deg ~ Poisson(4), P(>24) ~ 1e-12
constexpr int NBUK = 2;              // column buckets (col < n_src/2) for L3 locality
constexpr int NWE = 54 * 16384;      // prepped W elements per plane

// ---------------- static device heap ----------------
constexpr size_t AL(size_t x) { return (x + 255) & ~(size_t)255; }
constexpr size_t OFF_XIN = 0;
constexpr size_t OFF_XA  = AL(OFF_XIN + (size_t)NTP * 128 * 2);
constexpr size_t OFF_XB  = AL(OFF_XA  + (size_t)NTP * 128 * 2);
constexpr size_t OFF_WHI = AL(OFF_XB  + (size_t)NTP * 128 * 2);
constexpr size_t OFF_WLO = AL(OFF_WHI + (size_t)NWE * 2);
constexpr size_t OFF_ELL = AL(OFF_WLO + (size_t)NWE * 2);
constexpr size_t OFF_CNT = AL(OFF_ELL + (size_t)CNT_TOT * NBUK * ELLW * 8);
constexpr size_t OFF_PL  = AL(OFF_CNT + (size_t)CNT_TOT * NBUK * 4);
constexpr size_t OFF_M   = AL(OFF_PL  + (size_t)cNHE * 128 * 4);
constexpr size_t HEAPSZ  = AL(OFF_M   + (size_t)128 * 16 * 4);

__device__ __align__(256) unsigned char g_heap[HEAPSZ];

// ---------------- helpers ----------------
__device__ __forceinline__ ushort f2bf(float f) {
    union { float f; uint32_t u; } v{f};
    uint32_t r = v.u + 0x7fffu + ((v.u >> 16) & 1u);
    return (ushort)(r >> 16);
}
__device__ __forceinline__ float bflo(uint32_t u) { union { uint32_t u; float f; } v{u << 16}; return v.f; }
__device__ __forceinline__ float bfhi(uint32_t u) { union { uint32_t u; float f; } v{u & 0xffff0000u}; return v.f; }

__device__ __forceinline__ void gl_lds16(const ushort* g, ushort* l) {
    __builtin_amdgcn_global_load_lds((const __attribute__((address_space(1))) void*)g,
                                     (__attribute__((address_space(3))) void*)l, 16, 0, 0);
}

__device__ __forceinline__ void acc8(float* a, uint4 v, float s) {
    a[0] += s * bflo(v.x); a[1] += s * bfhi(v.x);
    a[2] += s * bflo(v.y); a[3] += s * bfhi(v.y);
    a[4] += s * bflo(v.z); a[5] += s * bfhi(v.z);
    a[6] += s * bflo(v.w); a[7] += s * bfhi(v.w);
}

// ---------------- descriptor structs ----------------
struct BD { const int* rows; const int* cols; const float* vals; int nnz; int cnt_off; int halfcol; };

struct FT { const ushort* xs; int cntb; int wm; };   // term source; cntb only used for gather terms
struct FG { ushort* xo; int n; FT t[6]; };

// ---------------- utility kernels ----------------
__global__ void kzero_i(int* p, int n) {
    for (int i = blockIdx.x * 256 + threadIdx.x; i < n; i += gridDim.x * 256) p[i] = 0;
}

__global__ void kcvt(const float4* __restrict__ src, uint2* __restrict__ dst, int n4) {
    int i = blockIdx.x * 256 + threadIdx.x;
    if (i >= n4) return;
    float4 v = src[i];
    dst[i] = make_uint2((uint32_t)f2bf(v.x) | ((uint32_t)f2bf(v.y) << 16),
                        (uint32_t)f2bf(v.z) | ((uint32_t)f2bf(v.w) << 16));
}

// W prep: split into hi/lo bf16, arranged for direct 16B fragment loads.
// layout idx = ((kf*8+cf)*64 + lane)*8 + i  -> element (k = kf*32+(lane>>4)*8+i, c = cf*16+(lane&15))
__global__ void kwprep(const float* __restrict__ W, ushort* __restrict__ whi, ushort* __restrict__ wlo) {
    int t = blockIdx.x * 256 + threadIdx.x;
    if (t >= NWE) return;
    int mat = t >> 14, r = t & 16383;
    int i = r & 7, l = (r >> 3) & 63, cf = (r >> 9) & 7, kf = r >> 12;
    int k = kf * 32 + (l >> 4) * 8 + i;
    int c = cf * 16 + (l & 15);
    float w = W[(size_t)mat * 16384 + k * 128 + c];
    ushort h = f2bf(w);
    union { uint32_t u; float f; } hv{(uint32_t)h << 16};
    whi[t] = h;
    wlo[t] = f2bf(w - hv.f);
}

// ---------------- one-pass bucketed ELL build, ONE matrix per launch ----------------
// Per-matrix serialization keeps its ELL region L2/L3-resident during the build
// (write coalescing); bucket = (col >= halfcol) partitions records so the fused
// gather's random x reads hit an L3-resident half at a time.
__global__ __launch_bounds__(256) void kscat_1m(BD b, int* __restrict__ cnt, uint2* __restrict__ ell) {
#pragma unroll
    for (int k = 0; k < 4; ++k) {
        int e = blockIdx.x * 1024 + k * 256 + threadIdx.x;
        if (e < b.nnz) {
            int r = b.rows[e];
            int c = b.cols[e];
            int bkt = (c >= b.halfcol) ? 1 : 0;
            size_t slot = (size_t)(b.cnt_off + r) * NBUK + bkt;
            int pos = atomicAdd(&cnt[slot], 1);
            if (pos < ELLW)
                ell[slot * ELLW + pos] = make_uint2((uint32_t)c, __float_as_uint(b.vals[e]));
        }
    }
}

// ---------------- fused gather + MFMA GEMM + tanh ----------------
// 64-row x 128-col output tile, 256 threads / 4 waves, homogeneous.
// Term 0 is statically the dense self term; terms 1..NT-1 are bucketed ELL gathers.
// ELL/cnt loads are non-temporal (streamed once); x random reads per bucket hit
// an L3-resident 26-51 MB half of the source.
template <int NT>
__global__ __launch_bounds__(256, 4) void kfused(FG g, const ushort* __restrict__ whi,
                                                 const ushort* __restrict__ wlo,
                                                 const int* __restrict__ cnt,
                                                 const uint2* __restrict__ ell) {
    __shared__ __align__(16) ushort xt[64 * 128];   // 16 KB
    const int row0 = blockIdx.x * 64;
    const int tid = threadIdx.x;
    const int lane = tid & 63, wv = tid >> 6;
    const int l15 = lane & 15, hi4 = lane >> 4;

    f4v acc[8];
    f4v zz = {0.f, 0.f, 0.f, 0.f};
#pragma unroll
    for (int cf = 0; cf < 8; ++cf) acc[cf] = zz;

#pragma unroll
    for (int t = 0; t < NT; ++t) {
        const FT ft = g.t[t];            // static index (t is unroll constant)
        if (t == 0) {
            // dense self term: global->LDS, source pre-swizzled (slot ^= row&7)
            const ushort* xb = ft.xs + (size_t)row0 * 128;
#pragma unroll
            for (int it = 0; it < 4; ++it) {
                int seg = it * 4 + wv;          // 16 wave-segments of 1 KB
                int u = seg * 64 + lane;        // 16B-unit index 0..1023
                int r = u >> 4, c16 = u & 15;
                gl_lds16(xb + (size_t)r * 128 + ((c16 ^ (r & 7)) * 8), &xt[seg * 512]);
            }
        } else {
            // bucketed gather: 16 threads/row x 8 cols, masked batch-4 pipeline
#pragma unroll
            for (int p = 0; p < 4; ++p) {
                int r = p * 16 + (tid >> 4);
                int cs = tid & 15;
                int absr = row0 + r;
                float a[8];
#pragma unroll
                for (int j = 0; j < 8; ++j) a[j] = 0.f;
                uint2 degs = make_uint2(0, 0);
                if (absr < g.n)
                    degs = *(const uint2*)&cnt[(size_t)(ft.cntb + absr) * NBUK];
                const ushort* xsrc = ft.xs + cs * 8;
#pragma unroll
                for (int b = 0; b < NBUK; ++b) {
                    int deg = b ? degs.y : degs.x;
                    deg = deg > ELLW ? ELLW : deg;
                    const uint2* er = ell + ((size_t)(ft.cntb + absr) * NBUK + b) * ELLW;
                    for (int e = 0; e < deg; e += 4) {
                        u4v r01 = __builtin_nontemporal_load((const u4v*)(er + e));
                        u4v r23 = __builtin_nontemporal_load((const u4v*)(er + e + 2));
                        uint32_t c0 = r01.x;
                        uint32_t c1 = (e + 1 < deg) ? r01.z : 0u;
                        uint32_t c2 = (e + 2 < deg) ? r23.x : 0u;
                        uint32_t c3 = (e + 3 < deg) ? r23.z : 0u;
                        float s0 = __uint_as_float(r01.y);
                        float s1 = (e + 1 < deg) ? __uint_as_float(r01.w) : 0.f;
                        float s2 = (e + 2 < deg) ? __uint_as_float(r23.y) : 0.f;
                        float s3 = (e + 3 < deg) ? __uint_as_float(r23.w) : 0.f;
                        uint4 x0 = *(const uint4*)(xsrc + (size_t)c0 * 128);
                        uint4 x1 = *(const uint4*)(xsrc + (size_t)c1 * 128);
                        uint4 x2 = *(const uint4*)(xsrc + (size_t)c2 * 128);
                        uint4 x3 = *(const uint4*)(xsrc + (size_t)c3 * 128);
                        acc8(a, x0, s0);
                        acc8(a, x1, s1);
                        acc8(a, x2, s2);
                        acc8(a, x3, s3);
                    }
                }
                uint32_t w[4];
#pragma unroll
                for (int j = 0; j < 4; ++j)
                    w[j] = (uint32_t)f2bf(a[2 * j]) | ((uint32_t)f2bf(a[2 * j + 1]) << 16);
                int c = cs ^ (r & 7);
                *(uint4*)&xt[r * 128 + c * 8] = make_uint4(w[0], w[1], w[2], w[3]);
            }
        }
        __syncthreads();

        // MFMA: acc += (W^T frag) x (g^T frag), hi + lo weight planes
        const int mat = ft.wm;
        const int rl = wv * 16 + l15;
#pragma unroll
        for (int h = 0; h < 2; ++h) {
            const ushort* wb = (h ? wlo : whi) + (size_t)mat * 16384;
#pragma unroll
            for (int kf = 0; kf < 4; ++kf) {
                int slot = (kf * 4 + hi4) ^ (rl & 7);
                bf8 xf = *(const bf8*)&xt[rl * 128 + slot * 8];
#pragma unroll
                for (int cfc = 0; cfc < 2; ++cfc) {
                    bf8 wf[4];
#pragma unroll
                    for (int c = 0; c < 4; ++c)
                        wf[c] = *(const bf8*)(wb + ((size_t)(kf * 8 + cfc * 4 + c) * 64 + lane) * 8);
#pragma unroll
                    for (int c = 0; c < 4; ++c)
                        acc[cfc * 4 + c] =
                            __builtin_amdgcn_mfma_f32_16x16x32_bf16(wf[c], xf, acc[cfc * 4 + c], 0, 0, 0);
                }
            }
        }
        __syncthreads();   // xt reads done before next term overwrites
    }

    // epilogue: tanh -> bf16 -> wave-private swizzled LDS stage -> coalesced store
    ushort* sb = xt + wv * 2048;   // 16 rows x 128 cols per wave
#pragma unroll
    for (int cf = 0; cf < 8; ++cf) {
        int rl = l15;
        float t0 = tanhf(acc[cf][0]), t1 = tanhf(acc[cf][1]);
        float t2 = tanhf(acc[cf][2]), t3 = tanhf(acc[cf][3]);
        uint32_t p0 = (uint32_t)f2bf(t0) | ((uint32_t)f2bf(t1) << 16);
        uint32_t p1 = (uint32_t)f2bf(t2) | ((uint32_t)f2bf(t3) << 16);
        int s0 = cf * 2 + (hi4 >> 1);
        int byteoff = rl * 256 + ((s0 ^ (rl & 7)) * 16) + (hi4 & 1) * 8;
        *(uint2*)((char*)sb + byteoff) = make_uint2(p0, p1);
    }
    __syncthreads();
    ushort* yb = g.xo + (size_t)(row0 + wv * 16) * 128;
#pragma unroll
    for (int it = 0; it < 4; ++it) {
        int rl = it * 4 + hi4;
        int s = l15 ^ (rl & 7);
        uint4 v = *(const uint4*)((const char*)sb + rl * 256 + s * 16);
        int absrow = row0 + wv * 16 + rl;
        if (absrow < g.n)
            *(uint4*)(yb + (size_t)rl * 128 + l15 * 8) = v;
    }
}

// ---------------- pooling + head ----------------
__device__ inline int lbound(const int* arr, int n, int key) {
    int lo = 0, hi = n;
    while (lo < hi) { int mid = (lo + hi) >> 1; if (arr[mid] < key) lo = mid + 1; else hi = mid; }
    return lo;
}

__global__ __launch_bounds__(128) void kpool(const ushort* x0, const int* he_idx, const int* he_seg, float* pool) {
    int s = blockIdx.x;
    int t = threadIdx.x;
    int lo = lbound(he_seg, cHE, s);
    int hi = lbound(he_seg, cHE, s + 1);
    float acc = 0.f;
    for (int e = lo; e < hi; ++e) acc += bflo((uint32_t)x0[(size_t)he_idx[e] * 128 + t]);
    float c = (float)(hi - lo);
    pool[(size_t)s * 128 + t] = acc / fmaxf(c, 1.f);
}

__global__ void kmatm(const float* Wfc, const float* Wcls, float* M) {
    int o = blockIdx.x * 256 + threadIdx.x;
    if (o >= 128 * 16) return;
    int dd = o >> 4, j = o & 15;
    float s = 0.f;
    for (int c = 0; c < 128; ++c) s += Wfc[dd * 128 + c] * Wcls[c * 16 + j];
    M[o] = s;
}

__global__ __launch_bounds__(256) void khead(const float* pool, const float* M, const float* bcls, float* out) {
    int row = blockIdx.x * 16 + (threadIdx.x >> 4);
    int j = threadIdx.x & 15;
    if (row >= cNHE - 1) return;
    int s = row + 1;
    float acc = bcls[j];
    const float* p = pool + (size_t)s * 128;
    for (int dd = 0; dd < 128; ++dd) acc += p[dd] * M[dd * 16 + j];
    out[(size_t)row * 16 + j] = acc;
}

// ---------------- host driver ----------------
extern "C" void kernel_launch(void* const* d_in, const int* in_sizes, int n_in,
                              void* d_out, int out_size, void* d_ws, size_t ws_size,
                              hipStream_t stream) {
    (void)in_sizes; (void)n_in; (void)out_size; (void)d_ws; (void)ws_size;

    unsigned char* heap = nullptr;
    hipGetSymbolAddress((void**)&heap, HIP_SYMBOL(g_heap));

    ushort* xin = (ushort*)(heap + OFF_XIN);
    ushort* xA  = (ushort*)(heap + OFF_XA);
    ushort* xB  = (ushort*)(heap + OFF_XB);
    ushort* whi = (ushort*)(heap + OFF_WHI);
    ushort* wlo = (ushort*)(heap + OFF_WLO);
    uint2* ell  = (uint2*)(heap + OFF_ELL);
    int* cnt    = (int*)(heap + OFF_CNT);
    float* pool = (float*)(heap + OFF_PL);
    float* Mbuf = (float*)(heap + OFF_M);

    const float* X0 = (const float*)d_in[0];
    const float* X1 = (const float*)d_in[1];
    const float* X2 = (const float*)d_in[2];
    const float* Wp = (const float*)d_in[29];

    // convert inputs to bf16 (padded segment bases)
    kcvt<<<dim3((cN0 * 32 + 255) / 256), 256, 0, stream>>>((const float4*)X0, (uint2*)xin, cN0 * 32);
    kcvt<<<dim3((cN1 * 32 + 255) / 256), 256, 0, stream>>>((const float4*)X1, (uint2*)(xin + (size_t)N0p * 128), cN1 * 32);
    kcvt<<<dim3((cN2 * 32 + 255) / 256), 256, 0, stream>>>((const float4*)X2, (uint2*)(xin + (size_t)(N0p + N1p) * 128), cN2 * 32);
    kwprep<<<dim3((NWE + 255) / 256), 256, 0, stream>>>(Wp, whi, wlo);

    // --- matrix descriptors (row-count bases into cnt/ell) ---
    static const int mnnz[13] = {800000, 800000, 800000, 1600000, 1600000, 1600000,
                                 800000, 800000, 800000, 400000, 400000, 300000, 300000};
    static const int mn[13] = {cN0, cN0, cN0, cN1, cN1, cN1, cN2, cN2, cN2, cN0, cN1, cN1, cN2};
    static const int mhalf[13] = {cN0 / 2, cN0 / 2, cN0 / 2, cN1 / 2, cN1 / 2, cN1 / 2,
                                  cN2 / 2, cN2 / 2, cN2 / 2, cN1 / 2, cN0 / 2, cN2 / 2, cN1 / 2};

    BD bs[13];
    int cb[13];
    {
        int coff = 0;
        for (int m = 0; m < 13; ++m) {
            BD& b = bs[m];
            if (m < 9) {
                const int* p = (const int*)d_in[3 + 2 * m];
                b.rows = p;
                b.cols = p + mnnz[m];
                b.vals = (const float*)d_in[4 + 2 * m];
            } else if (m == 9) { b.rows = (const int*)d_in[21]; b.cols = (const int*)d_in[22]; b.vals = (const float*)d_in[23]; }
            else if (m == 10) { b.rows = (const int*)d_in[22]; b.cols = (const int*)d_in[21]; b.vals = (const float*)d_in[23]; }
            else if (m == 11) { b.rows = (const int*)d_in[24]; b.cols = (const int*)d_in[25]; b.vals = (const float*)d_in[26]; }
            else              { b.rows = (const int*)d_in[25]; b.cols = (const int*)d_in[24]; b.vals = (const float*)d_in[26]; }
            b.nnz = mnnz[m];
            b.cnt_off = coff;
            b.halfcol = mhalf[m];
            cb[m] = coff;
            coff += mn[m];
        }
    }

    // --- bucketed ELL build: one launch per matrix (L3 write-coalescing) ---
    kzero_i<<<dim3(2048), 256, 0, stream>>>(cnt, CNT_TOT * NBUK);
    for (int m = 0; m < 13; ++m)
        kscat_1m<<<dim3((bs[m].nnz + 1023) / 1024), 256, 0, stream>>>(bs[m], cnt, ell);

    constexpr int nb0 = N0p / 64, nb1 = N1p / 64, nb2 = N2p / 64;  // 1564, 3126, 1564

    for (int l = 0; l < 3; ++l) {
        const ushort* xi = (l == 0) ? xin : ((l == 1) ? xA : xB);
        ushort* xo = (l == 1) ? xB : xA;
        const ushort* x0p = xi;
        const ushort* x1p = xi + (size_t)N0p * 128;
        const ushort* x2p = xi + (size_t)(N0p + N1p) * 128;
        auto M_ = [&](int s, int t) { return (l * 3 + s) * 6 + t; };

        FG f0{xo, cN0,
              {{x0p, -1, M_(0,0)}, {x0p, cb[0], M_(0,1)}, {x0p, cb[1], M_(0,2)},
               {x0p, cb[2], M_(0,3)}, {x1p, cb[9], M_(0,5)}, {nullptr, 0, 0}}};
        kfused<5><<<dim3(nb0), 256, 0, stream>>>(f0, whi, wlo, cnt, ell);

        if (l < 2) {
            FG f1{xo + (size_t)N0p * 128, cN1,
                  {{x1p, -1, M_(1,0)}, {x1p, cb[3], M_(1,1)}, {x1p, cb[4], M_(1,2)},
                   {x1p, cb[5], M_(1,3)}, {x0p, cb[10], M_(1,4)}, {x2p, cb[11], M_(1,5)}}};
            kfused<6><<<dim3(nb1), 256, 0, stream>>>(f1, whi, wlo, cnt, ell);

            FG f2{xo + (size_t)(N0p + N1p) * 128, cN2,
                  {{x2p, -1, M_(2,0)}, {x2p, cb[6], M_(2,1)}, {x2p, cb[7], M_(2,2)},
                   {x2p, cb[8], M_(2,3)}, {x1p, cb[12], M_(2,4)}, {nullptr, 0, 0}}};
            kfused<5><<<dim3(nb2), 256, 0, stream>>>(f2, whi, wlo, cnt, ell);
        }
    }

    // --- pooling + head ---
    kpool<<<dim3(cNHE), 128, 0, stream>>>(xA, (const int*)d_in[27], (const int*)d_in[28], pool);
    kmatm<<<dim3(8), 256, 0, stream>>>((const float*)d_in[30], (const float*)d_in[31], Mbuf);
    khead<<<dim3((cNHE - 1 + 15) / 16), 256, 0, stream>>>(pool, Mbuf, (const float*)d_in[32], (float*)d_out);
}

// Round 10
// 3096.442 us; speedup vs baseline: 1.2370x; 1.2370x over previous
//
#include <hip/hip_runtime.h>
#include <cstdint>
#include <cstddef>

typedef float f4v __attribute__((ext_vector_type(4)));
typedef __bf16 bf8 __attribute__((ext_vector_type(8)));
typedef uint32_t u4v __attribute__((ext_vector_type(4)));
typedef uint32_t u2v __attribute__((ext_vector_type(2)));

// ---------------- problem constants ----------------
constexpr int cN0 = 100000, cN1 = 200000, cN2 = 100000;
constexpr int cNHE = 20000, cHE = 200000;
constexpr int N0p = 100096, N1p = 200064, N2p = 100096;   // padded to 64-row multiples
constexpr int NTP = N0p + N1p + N2p;
constexpr int CNT_TOT = 1800000;     // sum of row counts over 13 matrices
constexpr int ELLW = 32;
constexpr int NWE = 54 * 16384;      // prepped W elements per plane

// ---------------- static device heap ----------------
constexpr size_t AL(size_t x) { return (x + 255) & ~(size_t)255; }
constexpr size_t OFF_XIN = 0;
constexpr size_t OFF_XA  = AL(OFF_XIN + (size_t)NTP * 128 * 2);
constexpr size_t OFF_XB  = AL(OFF_XA  + (size_t)NTP * 128 * 2);
constexpr size_t OFF_WHI = AL(OFF_XB  + (size_t)NTP * 128 * 2);
constexpr size_t OFF_WLO = AL(OFF_WHI + (size_t)NWE * 2);
constexpr size_t OFF_ELL = AL(OFF_WLO + (size_t)NWE * 2);
constexpr size_t OFF_CNT = AL(OFF_ELL + (size_t)CNT_TOT * ELLW * 8);
constexpr size_t OFF_PL  = AL(OFF_CNT + (size_t)CNT_TOT * 4);
constexpr size_t OFF_M   = AL(OFF_PL  + (size_t)cNHE * 128 * 4);
constexpr size_t HEAPSZ  = AL(OFF_M   + (size_t)128 * 16 * 4);

__device__ __align__(256) unsigned char g_heap[HEAPSZ];

// ---------------- helpers ----------------
__device__ __forceinline__ ushort f2bf(float f) {
    union { float f; uint32_t u; } v{f};
    uint32_t r = v.u + 0x7fffu + ((v.u >> 16) & 1u);
    return (ushort)(r >> 16);
}
__device__ __forceinline__ float bflo(uint32_t u) { union { uint32_t u; float f; } v{u << 16}; return v.f; }
__device__ __forceinline__ float bfhi(uint32_t u) { union { uint32_t u; float f; } v{u & 0xffff0000u}; return v.f; }

__device__ __forceinline__ void gl_lds16(const ushort* g, ushort* l) {
    __builtin_amdgcn_global_load_lds((const __attribute__((address_space(1))) void*)g,
                                     (__attribute__((address_space(3))) void*)l, 16, 0, 0);
}

__device__ __forceinline__ void acc8(float* a, uint4 v, float s) {
    a[0] += s * bflo(v.x); a[1] += s * bfhi(v.x);
    a[2] += s * bflo(v.y); a[3] += s * bfhi(v.y);
    a[4] += s * bflo(v.z); a[5] += s * bfhi(v.z);
    a[6] += s * bflo(v.w); a[7] += s * bfhi(v.w);
}

// ---------------- descriptor structs ----------------
struct BD { const int* rows; const int* cols; const float* vals; int nnz; int cnt_off; };

struct FT { const ushort* xs; int cntb; int wm; };   // term source; cntb only used for gather terms
struct FG { ushort* xo; int n; FT t[6]; };

// ---------------- utility kernels ----------------
__global__ void kzero_i(int* p, int n) {
    for (int i = blockIdx.x * 256 + threadIdx.x; i < n; i += gridDim.x * 256) p[i] = 0;
}

__global__ void kcvt(const float4* __restrict__ src, uint2* __restrict__ dst, int n4) {
    int i = blockIdx.x * 256 + threadIdx.x;
    if (i >= n4) return;
    float4 v = src[i];
    dst[i] = make_uint2((uint32_t)f2bf(v.x) | ((uint32_t)f2bf(v.y) << 16),
                        (uint32_t)f2bf(v.z) | ((uint32_t)f2bf(v.w) << 16));
}

// W prep: split into hi/lo bf16, arranged for direct 16B fragment loads.
// layout idx = ((kf*8+cf)*64 + lane)*8 + i  -> element (k = kf*32+(lane>>4)*8+i, c = cf*16+(lane&15))
__global__ void kwprep(const float* __restrict__ W, ushort* __restrict__ whi, ushort* __restrict__ wlo) {
    int t = blockIdx.x * 256 + threadIdx.x;
    if (t >= NWE) return;
    int mat = t >> 14, r = t & 16383;
    int i = r & 7, l = (r >> 3) & 63, cf = (r >> 9) & 7, kf = r >> 12;
    int k = kf * 32 + (l >> 4) * 8 + i;
    int c = cf * 16 + (l & 15);
    float w = W[(size_t)mat * 16384 + k * 128 + c];
    ushort h = f2bf(w);
    union { uint32_t u; float f; } hv{(uint32_t)h << 16};
    whi[t] = h;
    wlo[t] = f2bf(w - hv.f);
}

// ---------------- one-pass ELL build, ONE matrix per launch ----------------
// Per-matrix serialization keeps each <=51 MB ELL region L2/L3-resident during
// its build, so same-row records coalesce into single line writebacks.
__global__ __launch_bounds__(256) void kscat_1m(BD b, int* __restrict__ cnt, uint2* __restrict__ ell) {
#pragma unroll
    for (int k = 0; k < 4; ++k) {
        int e = blockIdx.x * 1024 + k * 256 + threadIdx.x;
        if (e < b.nnz) {
            int r = b.rows[e];
            int pos = atomicAdd(&cnt[b.cnt_off + r], 1);
            if (pos < ELLW)
                ell[((size_t)(b.cnt_off + r) << 5) + pos] =
                    make_uint2((uint32_t)b.cols[e], __float_as_uint(b.vals[e]));
        }
    }
}

// ---------------- fused gather + MFMA GEMM + tanh ----------------
// 64-row x 128-col output tile, 512 threads / 8 waves at (512,4) -> 32 waves/CU.
// Wave w owns rows [(w>>1)*16,+16) x cols [(w&1)*64,+64) -> acc[4] = 16 AGPRs,
// leaving ~112 arch regs for the gather pipeline (statically indexed, no spill).
template <int NT>
__global__ __launch_bounds__(512, 4) void kfused(FG g, const ushort* __restrict__ whi,
                                                 const ushort* __restrict__ wlo,
                                                 const int* __restrict__ cnt,
                                                 const uint2* __restrict__ ell) {
    __shared__ __align__(16) ushort xt[64 * 128];   // 16 KB
    const int row0 = blockIdx.x * 64;
    const int tid = threadIdx.x;
    const int lane = tid & 63, wv = tid >> 6;
    const int l15 = lane & 15, hi4 = lane >> 4;

    f4v acc[4];
    f4v zz = {0.f, 0.f, 0.f, 0.f};
#pragma unroll
    for (int cf = 0; cf < 4; ++cf) acc[cf] = zz;

#pragma unroll
    for (int t = 0; t < NT; ++t) {
        const FT ft = g.t[t];            // static index (t is unroll constant)
        if (t == 0) {
            // dense self term: global->LDS, source pre-swizzled (slot ^= row&7)
            const ushort* xb = ft.xs + (size_t)row0 * 128;
#pragma unroll
            for (int it = 0; it < 2; ++it) {
                int seg = it * 8 + wv;          // 16 wave-segments of 1 KB
                int u = seg * 64 + lane;        // 16B-unit index 0..1023
                int r = u >> 4, c16 = u & 15;
                gl_lds16(xb + (size_t)r * 128 + ((c16 ^ (r & 7)) * 8), &xt[seg * 512]);
            }
        } else {
            // gather term: g = A.x, 16 threads/row x 8 cols, batched-4 edge pipeline
#pragma unroll
            for (int p = 0; p < 2; ++p) {
                int r = p * 32 + (tid >> 4);
                int cs = tid & 15;
                int absr = row0 + r;
                float a[8];
#pragma unroll
                for (int j = 0; j < 8; ++j) a[j] = 0.f;
                const uint2* er = ell + ((size_t)(ft.cntb + absr) << 5);
                int deg = 0;
                if (absr < g.n) {
                    deg = __builtin_nontemporal_load(&cnt[ft.cntb + absr]);
                    deg = deg > ELLW ? ELLW : deg;
                }
                const ushort* xsrc = ft.xs + cs * 8;
                int e = 0;
                for (; e + 4 <= deg; e += 4) {
                    u4v r01 = __builtin_nontemporal_load((const u4v*)(er + e));
                    u4v r23 = __builtin_nontemporal_load((const u4v*)(er + e + 2));
                    uint4 x0 = *(const uint4*)(xsrc + (size_t)r01.x * 128);
                    uint4 x1 = *(const uint4*)(xsrc + (size_t)r01.z * 128);
                    uint4 x2 = *(const uint4*)(xsrc + (size_t)r23.x * 128);
                    uint4 x3 = *(const uint4*)(xsrc + (size_t)r23.z * 128);
                    acc8(a, x0, __uint_as_float(r01.y));
                    acc8(a, x1, __uint_as_float(r01.w));
                    acc8(a, x2, __uint_as_float(r23.y));
                    acc8(a, x3, __uint_as_float(r23.w));
                }
                for (; e < deg; ++e) {
                    u2v rc = __builtin_nontemporal_load((const u2v*)(er + e));
                    uint4 xv = *(const uint4*)(xsrc + (size_t)rc.x * 128);
                    acc8(a, xv, __uint_as_float(rc.y));
                }
                uint32_t w[4];
#pragma unroll
                for (int j = 0; j < 4; ++j)
                    w[j] = (uint32_t)f2bf(a[2 * j]) | ((uint32_t)f2bf(a[2 * j + 1]) << 16);
                int c = cs ^ (r & 7);
                *(uint4*)&xt[r * 128 + c * 8] = make_uint4(w[0], w[1], w[2], w[3]);
            }
        }
        __syncthreads();

        // MFMA: acc += (W^T frag) x (g^T frag), hi + lo weight planes.
        // Wave covers col-half (wv&1): cf_global = (wv&1)*4 + c.
        const int mat = ft.wm;
        const int rl = (wv >> 1) * 16 + l15;
        const int cbase = (wv & 1) * 4;
#pragma unroll
        for (int h = 0; h < 2; ++h) {
            const ushort* wb = (h ? wlo : whi) + (size_t)mat * 16384;
#pragma unroll
            for (int kf = 0; kf < 4; ++kf) {
                int slot = (kf * 4 + hi4) ^ (rl & 7);
                bf8 xf = *(const bf8*)&xt[rl * 128 + slot * 8];
                bf8 wf[4];
#pragma unroll
                for (int c = 0; c < 4; ++c)
                    wf[c] = *(const bf8*)(wb + ((size_t)(kf * 8 + cbase + c) * 64 + lane) * 8);
#pragma unroll
                for (int c = 0; c < 4; ++c)
                    acc[c] = __builtin_amdgcn_mfma_f32_16x16x32_bf16(wf[c], xf, acc[c], 0, 0, 0);
            }
        }
        __syncthreads();   // xt reads done before next term overwrites
    }

    // epilogue: tanh -> bf16 -> wave-private swizzled LDS stage -> coalesced store
    // wave region: 16 rows x 64 cols x 2B = 2 KB at xt + wv*1024
    ushort* sb = xt + wv * 1024;
#pragma unroll
    for (int c = 0; c < 4; ++c) {
        int rl = l15;
        float t0 = tanhf(acc[c][0]), t1 = tanhf(acc[c][1]);
        float t2 = tanhf(acc[c][2]), t3 = tanhf(acc[c][3]);
        uint32_t p0 = (uint32_t)f2bf(t0) | ((uint32_t)f2bf(t1) << 16);
        uint32_t p1 = (uint32_t)f2bf(t2) | ((uint32_t)f2bf(t3) << 16);
        int byteoff = rl * 128 + ((c * 32 + hi4 * 8) ^ ((rl & 7) << 4));
        *(uint2*)((char*)sb + byteoff) = make_uint2(p0, p1);
    }
    __syncthreads();
    ushort* yb = g.xo + (size_t)(row0 + (wv >> 1) * 16) * 128 + (wv & 1) * 64;
#pragma unroll
    for (int it = 0; it < 2; ++it) {
        int rl = it * 8 + (lane >> 3);
        int u = lane & 7;
        uint4 v = *(const uint4*)((const char*)sb + rl * 128 + ((u * 16) ^ ((rl & 7) << 4)));
        int absrow = row0 + (wv >> 1) * 16 + rl;
        if (absrow < g.n)
            *(uint4*)(yb + (size_t)rl * 128 + u * 8) = v;
    }
}

// ---------------- pooling + head ----------------
__device__ inline int lbound(const int* arr, int n, int key) {
    int lo = 0, hi = n;
    while (lo < hi) { int mid = (lo + hi) >> 1; if (arr[mid] < key) lo = mid + 1; else hi = mid; }
    return lo;
}

__global__ __launch_bounds__(128) void kpool(const ushort* x0, const int* he_idx, const int* he_seg, float* pool) {
    int s = blockIdx.x;
    int t = threadIdx.x;
    int lo = lbound(he_seg, cHE, s);
    int hi = lbound(he_seg, cHE, s + 1);
    float acc = 0.f;
    for (int e = lo; e < hi; ++e) acc += bflo((uint32_t)x0[(size_t)he_idx[e] * 128 + t]);
    float c = (float)(hi - lo);
    pool[(size_t)s * 128 + t] = acc / fmaxf(c, 1.f);
}

__global__ void kmatm(const float* Wfc, const float* Wcls, float* M) {
    int o = blockIdx.x * 256 + threadIdx.x;
    if (o >= 128 * 16) return;
    int dd = o >> 4, j = o & 15;
    float s = 0.f;
    for (int c = 0; c < 128; ++c) s += Wfc[dd * 128 + c] * Wcls[c * 16 + j];
    M[o] = s;
}

__global__ __launch_bounds__(256) void khead(const float* pool, const float* M, const float* bcls, float* out) {
    int row = blockIdx.x * 16 + (threadIdx.x >> 4);
    int j = threadIdx.x & 15;
    if (row >= cNHE - 1) return;
    int s = row + 1;
    float acc = bcls[j];
    const float* p = pool + (size_t)s * 128;
    for (int dd = 0; dd < 128; ++dd) acc += p[dd] * M[dd * 16 + j];
    out[(size_t)row * 16 + j] = acc;
}

// ---------------- host driver ----------------
extern "C" void kernel_launch(void* const* d_in, const int* in_sizes, int n_in,
                              void* d_out, int out_size, void* d_ws, size_t ws_size,
                              hipStream_t stream) {
    (void)in_sizes; (void)n_in; (void)out_size; (void)d_ws; (void)ws_size;

    unsigned char* heap = nullptr;
    hipGetSymbolAddress((void**)&heap, HIP_SYMBOL(g_heap));

    ushort* xin = (ushort*)(heap + OFF_XIN);
    ushort* xA  = (ushort*)(heap + OFF_XA);
    ushort* xB  = (ushort*)(heap + OFF_XB);
    ushort* whi = (ushort*)(heap + OFF_WHI);
    ushort* wlo = (ushort*)(heap + OFF_WLO);
    uint2* ell  = (uint2*)(heap + OFF_ELL);
    int* cnt    = (int*)(heap + OFF_CNT);
    float* pool = (float*)(heap + OFF_PL);
    float* Mbuf = (float*)(heap + OFF_M);

    const float* X0 = (const float*)d_in[0];
    const float* X1 = (const float*)d_in[1];
    const float* X2 = (const float*)d_in[2];
    const float* Wp = (const float*)d_in[29];

    // convert inputs to bf16 (padded segment bases)
    kcvt<<<dim3((cN0 * 32 + 255) / 256), 256, 0, stream>>>((const float4*)X0, (uint2*)xin, cN0 * 32);
    kcvt<<<dim3((cN1 * 32 + 255) / 256), 256, 0, stream>>>((const float4*)X1, (uint2*)(xin + (size_t)N0p * 128), cN1 * 32);
    kcvt<<<dim3((cN2 * 32 + 255) / 256), 256, 0, stream>>>((const float4*)X2, (uint2*)(xin + (size_t)(N0p + N1p) * 128), cN2 * 32);
    kwprep<<<dim3((NWE + 255) / 256), 256, 0, stream>>>(Wp, whi, wlo);

    // --- matrix descriptors (row-count bases into cnt/ell) ---
    static const int mnnz[13] = {800000, 800000, 800000, 1600000, 1600000, 1600000,
                                 800000, 800000, 800000, 400000, 400000, 300000, 300000};
    static const int mn[13] = {cN0, cN0, cN0, cN1, cN1, cN1, cN2, cN2, cN2, cN0, cN1, cN1, cN2};

    BD bs[13];
    int cb[13];
    {
        int coff = 0;
        for (int m = 0; m < 13; ++m) {
            BD& b = bs[m];
            if (m < 9) {
                const int* p = (const int*)d_in[3 + 2 * m];
                b.rows = p;
                b.cols = p + mnnz[m];
                b.vals = (const float*)d_in[4 + 2 * m];
            } else if (m == 9) { b.rows = (const int*)d_in[21]; b.cols = (const int*)d_in[22]; b.vals = (const float*)d_in[23]; }
            else if (m == 10) { b.rows = (const int*)d_in[22]; b.cols = (const int*)d_in[21]; b.vals = (const float*)d_in[23]; }
            else if (m == 11) { b.rows = (const int*)d_in[24]; b.cols = (const int*)d_in[25]; b.vals = (const float*)d_in[26]; }
            else              { b.rows = (const int*)d_in[25]; b.cols = (const int*)d_in[24]; b.vals = (const float*)d_in[26]; }
            b.nnz = mnnz[m];
            b.cnt_off = coff;
            cb[m] = coff;
            coff += mn[m];
        }
    }

    // --- ELL build: one launch per matrix (L3 write-coalescing) ---
    kzero_i<<<dim3(2048), 256, 0, stream>>>(cnt, CNT_TOT);
    for (int m = 0; m < 13; ++m)
        kscat_1m<<<dim3((bs[m].nnz + 1023) / 1024), 256, 0, stream>>>(bs[m], cnt, ell);

    constexpr int nb0 = N0p / 64, nb1 = N1p / 64, nb2 = N2p / 64;  // 1564, 3126, 1564

    for (int l = 0; l < 3; ++l) {
        const ushort* xi = (l == 0) ? xin : ((l == 1) ? xA : xB);
        ushort* xo = (l == 1) ? xB : xA;
        const ushort* x0p = xi;
        const ushort* x1p = xi + (size_t)N0p * 128;
        const ushort* x2p = xi + (size_t)(N0p + N1p) * 128;
        auto M_ = [&](int s, int t) { return (l * 3 + s) * 6 + t; };

        FG f0{xo, cN0,
              {{x0p, -1, M_(0,0)}, {x0p, cb[0], M_(0,1)}, {x0p, cb[1], M_(0,2)},
               {x0p, cb[2], M_(0,3)}, {x1p, cb[9], M_(0,5)}, {nullptr, 0, 0}}};
        kfused<5><<<dim3(nb0), 512, 0, stream>>>(f0, whi, wlo, cnt, ell);

        if (l < 2) {
            FG f1{xo + (size_t)N0p * 128, cN1,
                  {{x1p, -1, M_(1,0)}, {x1p, cb[3], M_(1,1)}, {x1p, cb[4], M_(1,2)},
                   {x1p, cb[5], M_(1,3)}, {x0p, cb[10], M_(1,4)}, {x2p, cb[11], M_(1,5)}}};
            kfused<6><<<dim3(nb1), 512, 0, stream>>>(f1, whi, wlo, cnt, ell);

            FG f2{xo + (size_t)(N0p + N1p) * 128, cN2,
                  {{x2p, -1, M_(2,0)}, {x2p, cb[6], M_(2,1)}, {x2p, cb[7], M_(2,2)},
                   {x2p, cb[8], M_(2,3)}, {x1p, cb[12], M_(2,4)}, {nullptr, 0, 0}}};
            kfused<5><<<dim3(nb2), 512, 0, stream>>>(f2, whi, wlo, cnt, ell);
        }
    }

    // --- pooling + head ---
    kpool<<<dim3(cNHE), 128, 0, stream>>>(xA, (const int*)d_in[27], (const int*)d_in[28], pool);
    kmatm<<<dim3(8), 256, 0, stream>>>((const float*)d_in[30], (const float*)d_in[31], Mbuf);
    khead<<<dim3((cNHE - 1 + 15) / 16), 256, 0, stream>>>(pool, Mbuf, (const float*)d_in[32], (float*)d_out);
}